// Round 1
// baseline (350.576 us; speedup 1.0000x reference)
//
#include <hip/hip_runtime.h>
#include <math.h>

#define NB 8
#define NQ 128
#define NK 1024
#define ND 512   // QK_DIM
#define NH 256   // HID
#define NV 512   // VDIM
#define NEGV (-1e6f)

// ---------- wave helpers (wave64) ----------
__device__ __forceinline__ float wave_rmax(float v) {
#pragma unroll
  for (int off = 32; off; off >>= 1) v = fmaxf(v, __shfl_xor(v, off));
  return v;
}
__device__ __forceinline__ float wave_rsum(float v) {
#pragma unroll
  for (int off = 32; off; off >>= 1) v += __shfl_xor(v, off);
  return v;
}

// =====================================================================
// K1: fused projection + exp(2x) epilogue.
//   rows [0,1024)        : q rows -> Eq[b*NQ+q][h]          (layout [row][NH])
//   rows [1024, 1024+8192): k rows -> EkT[b][h][k]          (transposed store)
// grid = (NB*NQ + NB*NK)/32 = 288 blocks, 256 threads.
// Thread tile: 16 rows x 2 cols (tx = col, tx+128; ty picks row half).
// k-row blocks fully beyond valid_len are skipped (their EkT stays poison;
// K2 masks those scores to NEG before softmax, so it never matters).
// =====================================================================
__global__ __launch_bounds__(256) void proj_kernel(
    const float* __restrict__ queries, const float* __restrict__ keys,
    const float* __restrict__ Wq, const float* __restrict__ Wk,
    const int* __restrict__ valid_lens,
    float* __restrict__ Eq, float* __restrict__ EkT) {
  const int t  = threadIdx.x;
  const int tx = t & 127;
  const int ty = t >> 7;
  const int nqblk = (NB * NQ) / 32;  // 32
  const bool isQ = (int)blockIdx.x < nqblk;
  const float* A;
  const float* W;
  int row0, b = 0, rin = 0;
  if (isQ) {
    A = queries; W = Wq; row0 = blockIdx.x * 32;
  } else {
    row0 = ((int)blockIdx.x - nqblk) * 32;
    b = row0 / NK;
    rin = row0 % NK;
    if (rin >= valid_lens[b]) return;  // uniform per block: safe early-out
    A = keys; W = Wk;
  }

  __shared__ __align__(16) float As[32][32];
  float acc0[16], acc1[16];
#pragma unroll
  for (int r = 0; r < 16; ++r) { acc0[r] = 0.f; acc1[r] = 0.f; }

  for (int d0 = 0; d0 < ND; d0 += 32) {
    // stage A tile [32 rows][32 d]
#pragma unroll
    for (int i = 0; i < 4; ++i) {
      int idx = t + 256 * i;
      As[idx >> 5][idx & 31] = A[(size_t)(row0 + (idx >> 5)) * ND + d0 + (idx & 31)];
    }
    __syncthreads();
#pragma unroll
    for (int dg = 0; dg < 8; ++dg) {
      float wa[4], wb[4];
#pragma unroll
      for (int u = 0; u < 4; ++u) {
        wa[u] = W[(size_t)(d0 + dg * 4 + u) * NH + tx];
        wb[u] = W[(size_t)(d0 + dg * 4 + u) * NH + tx + 128];
      }
#pragma unroll
      for (int r = 0; r < 16; ++r) {
        float4 a = *(const float4*)&As[ty * 16 + r][dg * 4];
        acc0[r] += a.x * wa[0] + a.y * wa[1] + a.z * wa[2] + a.w * wa[3];
        acc1[r] += a.x * wb[0] + a.y * wb[1] + a.z * wb[2] + a.w * wb[3];
      }
    }
    __syncthreads();
  }

  const float C2 = 2.885390081777927f;  // 2*log2(e): exp2(C2*x) = e^{2x}
  if (isQ) {
#pragma unroll
    for (int r = 0; r < 16; ++r) {
      int row = row0 + ty * 16 + r;
      float p0 = fminf(fmaxf(acc0[r], -15.f), 15.f);
      float p1 = fminf(fmaxf(acc1[r], -15.f), 15.f);
      Eq[(size_t)row * NH + tx]       = exp2f(p0 * C2);
      Eq[(size_t)row * NH + tx + 128] = exp2f(p1 * C2);
    }
  } else {
    float e0[16], e1[16];
#pragma unroll
    for (int r = 0; r < 16; ++r) {
      float p0 = fminf(fmaxf(acc0[r], -15.f), 15.f);
      float p1 = fminf(fmaxf(acc1[r], -15.f), 15.f);
      e0[r] = exp2f(p0 * C2);
      e1[r] = exp2f(p1 * C2);
    }
    const int kbase = rin + ty * 16;
    float* o0 = &EkT[((size_t)b * NH + tx) * NK + kbase];
    float* o1 = &EkT[((size_t)b * NH + tx + 128) * NK + kbase];
#pragma unroll
    for (int rr = 0; rr < 4; ++rr) {
      *(float4*)&o0[rr * 4] = make_float4(e0[rr*4], e0[rr*4+1], e0[rr*4+2], e0[rr*4+3]);
      *(float4*)&o1[rr * 4] = make_float4(e1[rr*4], e1[rr*4+1], e1[rr*4+2], e1[rr*4+3]);
    }
  }
}

// =====================================================================
// K2: fused scores + masked softmax.
// grid = NB * NQ/4 = 256 blocks, 512 threads.
// Block covers 4 q rows; the two 256-thread halves each own 2 q rows so
// every EkT read feeds 2 q's (and the twin half re-hits it in L1).
// tanh(q+k) = 1 - 2/(Eq*Ek + 1);  score = sumW - 2*sum_h wv_h*rcp(P+1).
// j-blocks (k in [256j,256j+256)) beyond ceil(V/256) are skipped entirely.
// =====================================================================
template <int JM>
__device__ __forceinline__ void score_loop(const float* __restrict__ ekbase,
                                           const float (*__restrict__ eqs)[NH],
                                           const float* __restrict__ wvs,
                                           int tq, int tk, float acc[2][4]) {
#pragma unroll 2
  for (int h = 0; h < NH; ++h) {
    const float wvh = wvs[h];
    const float eq0 = eqs[tq * 2 + 0][h];
    const float eq1 = eqs[tq * 2 + 1][h];
    const float* ek = ekbase + (size_t)h * NK + tk;
#pragma unroll
    for (int j = 0; j < JM; ++j) {
      const float e = ek[256 * j];
      acc[0][j] += wvh * __builtin_amdgcn_rcpf(__builtin_fmaf(eq0, e, 1.f));
      acc[1][j] += wvh * __builtin_amdgcn_rcpf(__builtin_fmaf(eq1, e, 1.f));
    }
  }
}

__global__ __launch_bounds__(512) void score_softmax_kernel(
    const float* __restrict__ Eq, const float* __restrict__ EkT,
    const float* __restrict__ wv, const int* __restrict__ valid_lens,
    float* __restrict__ attn) {
  const int t    = threadIdx.x;
  const int tk   = t & 255;
  const int tq   = t >> 8;      // 0/1: which q-pair this half owns
  const int b    = blockIdx.x >> 5;
  const int q0   = (blockIdx.x & 31) * 4;
  const int V    = valid_lens[b];
  const int jmax = (V + 255) >> 8;
  const int lane = t & 63, wid = t >> 6;

  __shared__ float eqs[4][NH];
  __shared__ float wvs[NH];
  __shared__ float red[8];

  for (int i = t; i < 4 * NH; i += 512)
    eqs[i >> 8][i & 255] = Eq[(size_t)(b * NQ + q0 + (i >> 8)) * NH + (i & 255)];
  if (t < NH) wvs[t] = wv[t];
  __syncthreads();

  // sumW = sum_h wv[h] (waves 0-3 cover wv[0..255]; 4-7 duplicate)
  float sw = wave_rsum(wvs[tk]);
  if (lane == 0) red[wid] = sw;
  __syncthreads();
  const float sumW = red[0] + red[1] + red[2] + red[3];
  __syncthreads();

  float acc[2][4] = {{0.f, 0.f, 0.f, 0.f}, {0.f, 0.f, 0.f, 0.f}};
  const float* ekbase = EkT + (size_t)b * NH * NK;
  switch (jmax) {
    case 1:  score_loop<1>(ekbase, eqs, wvs, tq, tk, acc); break;
    case 2:  score_loop<2>(ekbase, eqs, wvs, tq, tk, acc); break;
    case 3:  score_loop<3>(ekbase, eqs, wvs, tq, tk, acc); break;
    default: score_loop<4>(ekbase, eqs, wvs, tq, tk, acc); break;
  }

  const int rb = tq * 4;
#pragma unroll
  for (int q = 0; q < 2; ++q) {
    float sc[4];
#pragma unroll
    for (int j = 0; j < 4; ++j) {
      int k = tk + 256 * j;
      sc[j] = (k < V) ? __builtin_fmaf(-2.f, acc[q][j], sumW) : NEGV;
    }
    float lm = wave_rmax(fmaxf(fmaxf(sc[0], sc[1]), fmaxf(sc[2], sc[3])));
    if (lane == 0) red[wid] = lm;
    __syncthreads();
    const float m = fmaxf(fmaxf(red[rb], red[rb + 1]), fmaxf(red[rb + 2], red[rb + 3]));
    __syncthreads();
    float e[4];
    float ls = 0.f;
#pragma unroll
    for (int j = 0; j < 4; ++j) { e[j] = __expf(sc[j] - m); ls += e[j]; }
    ls = wave_rsum(ls);
    if (lane == 0) red[wid] = ls;
    __syncthreads();
    const float s = red[rb] + red[rb + 1] + red[rb + 2] + red[rb + 3];
    __syncthreads();
    const float rs = __builtin_amdgcn_rcpf(s);
    float* arow = attn + (size_t)(b * NQ + q0 + tq * 2 + q) * NK + tk;
#pragma unroll
    for (int j = 0; j < 4; ++j) arow[256 * j] = e[j] * rs;  // zeros where invalid
  }
}

// =====================================================================
// K3: out[b,q,v] = sum_k attn[b,q,k] * values[b,k,v]
// grid = NB * (NQ/8) * 2 = 256 blocks, 256 threads.
// Block: (b, 8-q tile, half of V). Thread: 2 q rows x float4 of v.
// Loops k only up to ceil(V/64)*64 (attn is zero for k>=V, and fully
// written by K2 up to ceil(V/256)*256 >= that bound).
// =====================================================================
__global__ __launch_bounds__(256) void pv_kernel(
    const float* __restrict__ attn, const float* __restrict__ values,
    const int* __restrict__ valid_lens, float* __restrict__ out) {
  const int t    = threadIdx.x;
  const int bx   = blockIdx.x;
  const int b    = bx >> 5;
  const int rest = bx & 31;
  const int qt   = rest >> 1;  // 16 tiles of 8 q
  const int vh   = rest & 1;
  const int g    = t >> 6;     // wave id: 2 q rows each
  const int lane = t & 63;
  const int v4   = vh * 256 + lane * 4;
  const int V    = valid_lens[b];
  const int nkc  = (V + 63) >> 6;
  const int q0   = qt * 8;

  __shared__ float attnS[8][64];
  float4 acc0 = {0.f, 0.f, 0.f, 0.f}, acc1 = {0.f, 0.f, 0.f, 0.f};

  for (int kc = 0; kc < nkc; ++kc) {
#pragma unroll
    for (int i = 0; i < 2; ++i) {
      int idx = t + 256 * i;
      attnS[idx >> 6][idx & 63] =
          attn[(size_t)(b * NQ + q0 + (idx >> 6)) * NK + kc * 64 + (idx & 63)];
    }
    __syncthreads();
#pragma unroll 4
    for (int kk = 0; kk < 64; ++kk) {
      const float4 val = *(const float4*)&values[(size_t)(b * NK + kc * 64 + kk) * NV + v4];
      const float a0 = attnS[g * 2 + 0][kk];
      const float a1 = attnS[g * 2 + 1][kk];
      acc0.x += a0 * val.x; acc0.y += a0 * val.y; acc0.z += a0 * val.z; acc0.w += a0 * val.w;
      acc1.x += a1 * val.x; acc1.y += a1 * val.y; acc1.z += a1 * val.z; acc1.w += a1 * val.w;
    }
    __syncthreads();
  }
  const int q = q0 + g * 2;
  *(float4*)&out[(size_t)(b * NQ + q) * NV + v4]     = acc0;
  *(float4*)&out[(size_t)(b * NQ + q + 1) * NV + v4] = acc1;
}

// =====================================================================
extern "C" void kernel_launch(void* const* d_in, const int* in_sizes, int n_in,
                              void* d_out, int out_size, void* d_ws, size_t ws_size,
                              hipStream_t stream) {
  const float* queries = (const float*)d_in[0];
  const float* keys    = (const float*)d_in[1];
  const float* values  = (const float*)d_in[2];
  const int*   vlens   = (const int*)d_in[3];
  const float* Wq      = (const float*)d_in[4];
  const float* Wk      = (const float*)d_in[5];
  const float* wv      = (const float*)d_in[6];
  float* out = (float*)d_out;

  float* ws   = (float*)d_ws;
  float* Eq   = ws;                              // NB*NQ*NH   = 262144 f32
  float* EkT  = ws + 262144;                     // NB*NH*NK   = 2097152 f32
  float* attn = ws + 262144 + 2097152;           // NB*NQ*NK   = 1048576 f32
  // total: 13.6 MB of ws

  proj_kernel<<<dim3(288), dim3(256), 0, stream>>>(queries, keys, Wq, Wk, vlens, Eq, EkT);
  score_softmax_kernel<<<dim3(256), dim3(512), 0, stream>>>(Eq, EkT, wv, vlens, attn);
  pv_kernel<<<dim3(256), dim3(256), 0, stream>>>(attn, values, vlens, out);
}

// Round 2
// 231.992 us; speedup vs baseline: 1.5112x; 1.5112x over previous
//
#include <hip/hip_runtime.h>
#include <math.h>

#define NB 8
#define NQ 128
#define NK 1024
#define ND 512   // QK_DIM
#define NH 256   // HID
#define NV 512   // VDIM
#define NEGV (-1e6f)

// ---------- wave helpers (wave64) ----------
__device__ __forceinline__ float wave_rmax(float v) {
#pragma unroll
  for (int off = 32; off; off >>= 1) v = fmaxf(v, __shfl_xor(v, off));
  return v;
}
__device__ __forceinline__ float wave_rsum(float v) {
#pragma unroll
  for (int off = 32; off; off >>= 1) v += __shfl_xor(v, off);
  return v;
}

// =====================================================================
// K1: fused projection + exp(2x) epilogue.  C = A @ W, then e^{2C}.
// Output tile 64 rows x 64 cols per block, 256 threads, 4x4 per thread.
// grid = dim3(144 row-blocks, 4 col-blocks). Row-blocks 0..15 are the
// 1024 q rows -> Eq[row][h]; 16..143 are the 8192 k rows -> EkT[b][h][k]
// (transposed store, float4 along k). k row-blocks fully beyond
// valid_len[b] exit immediately (downstream masks those k).
// LDS: A tile [64][36] (pad 36 keeps float4 16B-aligned & spreads banks),
// W tile transposed [col][d] = [64][36].
// =====================================================================
__global__ __launch_bounds__(256) void proj_kernel(
    const float* __restrict__ queries, const float* __restrict__ keys,
    const float* __restrict__ Wq, const float* __restrict__ Wk,
    const int* __restrict__ valid_lens,
    float* __restrict__ Eq, float* __restrict__ EkT) {
  const int t  = threadIdx.x;
  const int tx = t & 15;   // col group: cols tx + 16u
  const int ty = t >> 4;   // row group: rows ty*4 + r
  const int c0 = blockIdx.y * 64;
  const int bx = blockIdx.x;
  const bool isQ = bx < 16;
  const float* A;
  const float* W;
  int row0, b = 0, rin = 0;
  if (isQ) {
    A = queries; W = Wq; row0 = bx * 64;
  } else {
    int rg = (bx - 16) * 64;
    b = rg >> 10;
    rin = rg & 1023;
    if (rin >= valid_lens[b]) return;  // uniform per block
    A = keys; W = Wk; row0 = rg;
  }

  __shared__ __align__(16) float As[64][36];
  __shared__ __align__(16) float Ws[64][36];  // [col][d]

  float acc[4][4];
#pragma unroll
  for (int r = 0; r < 4; ++r)
#pragma unroll
    for (int u = 0; u < 4; ++u) acc[r][u] = 0.f;

  for (int d0 = 0; d0 < ND; d0 += 32) {
    // stage A tile 64x32 (float4 global, float4 LDS)
#pragma unroll
    for (int i = 0; i < 2; ++i) {
      int id = t + 256 * i;          // 0..511
      int r = id >> 3, c4 = id & 7;
      float4 v = *(const float4*)&A[(size_t)(row0 + r) * ND + d0 + c4 * 4];
      *(float4*)&As[r][c4 * 4] = v;
    }
    // stage W tile 32x64 transposed -> Ws[col][d]
#pragma unroll
    for (int i = 0; i < 8; ++i) {
      int dr = (t >> 6) + 4 * i;     // 0..31
      int cl = t & 63;
      Ws[cl][dr] = W[(size_t)(d0 + dr) * NH + c0 + cl];
    }
    __syncthreads();
#pragma unroll
    for (int dd = 0; dd < 32; dd += 4) {
      float4 a4[4], w4[4];
#pragma unroll
      for (int r = 0; r < 4; ++r) a4[r] = *(const float4*)&As[ty * 4 + r][dd];
#pragma unroll
      for (int u = 0; u < 4; ++u) w4[u] = *(const float4*)&Ws[tx + 16 * u][dd];
#pragma unroll
      for (int r = 0; r < 4; ++r)
#pragma unroll
        for (int u = 0; u < 4; ++u) {
          acc[r][u] += a4[r].x * w4[u].x + a4[r].y * w4[u].y +
                       a4[r].z * w4[u].z + a4[r].w * w4[u].w;
        }
    }
    __syncthreads();
  }

  const float C2 = 2.885390081777927f;  // 2*log2(e): exp2(C2*x) = e^{2x}
  if (isQ) {
#pragma unroll
    for (int r = 0; r < 4; ++r) {
      int row = row0 + ty * 4 + r;
#pragma unroll
      for (int u = 0; u < 4; ++u) {
        float p = fminf(fmaxf(acc[r][u], -15.f), 15.f);
        Eq[(size_t)row * NH + c0 + tx + 16 * u] = exp2f(p * C2);
      }
    }
  } else {
#pragma unroll
    for (int u = 0; u < 4; ++u) {
      int h = c0 + tx + 16 * u;
      float e[4];
#pragma unroll
      for (int r = 0; r < 4; ++r) {
        float p = fminf(fmaxf(acc[r][u], -15.f), 15.f);
        e[r] = exp2f(p * C2);
      }
      // 4 consecutive k (= rows) -> float4 along k
      *(float4*)&EkT[((size_t)b * NH + h) * NK + rin + ty * 4] =
          make_float4(e[0], e[1], e[2], e[3]);
    }
  }
}

// =====================================================================
// K2: scores only (no softmax -> no block-wide sync -> full parallelism).
// grid = dim3(32 q-tiles, 4 k-tiles, 8 b), 256 threads; thread owns one k
// and 4 q rows. k-tiles beyond valid_len exit immediately.
// tanh(q+k) = 1 - 2/(Eq*Ek+1); score = sumW - 2*sum_h wv_h*rcp(P+1).
// =====================================================================
__global__ __launch_bounds__(256) void score_kernel(
    const float* __restrict__ Eq, const float* __restrict__ EkT,
    const float* __restrict__ wv, const int* __restrict__ valid_lens,
    float* __restrict__ scores) {
  const int b = blockIdx.z;
  const int V = valid_lens[b];
  const int k0 = blockIdx.y * 256;
  if (k0 >= V) return;  // uniform
  const int t = threadIdx.x;
  const int q0 = blockIdx.x * 4;

  __shared__ __align__(16) float eqs[4][NH];
  __shared__ float wvs[NH];
  __shared__ float redS[4];

  {  // stage Eq rows (4x256 floats = one float4 per thread)
    int q = t >> 6, c4 = t & 63;
    *(float4*)&eqs[q][c4 * 4] =
        *(const float4*)&Eq[(size_t)(b * NQ + q0 + q) * NH + c4 * 4];
  }
  wvs[t] = wv[t];  // 256 == NH
  __syncthreads();

  float sw = wave_rsum(wvs[t]);
  if ((t & 63) == 0) redS[t >> 6] = sw;
  __syncthreads();
  const float sumW = redS[0] + redS[1] + redS[2] + redS[3];

  float acc[4] = {0.f, 0.f, 0.f, 0.f};
  const float* ekp = EkT + (size_t)b * NH * NK + k0 + t;
#pragma unroll 8
  for (int h = 0; h < NH; ++h) {
    const float e = ekp[(size_t)h * NK];
    const float w = wvs[h];
#pragma unroll
    for (int q = 0; q < 4; ++q)
      acc[q] += w * __builtin_amdgcn_rcpf(__builtin_fmaf(eqs[q][h], e, 1.f));
  }

  const int k = k0 + t;
#pragma unroll
  for (int q = 0; q < 4; ++q)
    scores[(size_t)(b * NQ + q0 + q) * NK + k] =
        (k < V) ? __builtin_fmaf(-2.f, acc[q], sumW) : NEGV;
}

// =====================================================================
// K3: fused masked-softmax + PV.
// grid = dim3(16 q-tiles of 8 rows, 4 v-quarters of 128 cols, 8 b), 256 thr.
// Stage 8 score rows in LDS (32 KB), per-wave (2 rows each) max/exp/sum
// in place; 1/s folded into the accumulator epilogue. PV: lane = half-row
// x float4-col; values read as coalesced float4 from L2.
// =====================================================================
__global__ __launch_bounds__(256) void softmax_pv_kernel(
    const float* __restrict__ scores, const float* __restrict__ values,
    const int* __restrict__ valid_lens, float* __restrict__ out) {
  const int qt = blockIdx.x;   // 16
  const int vq = blockIdx.y;   // 4
  const int b  = blockIdx.z;   // 8
  const int V  = valid_lens[b];
  const int Vc = (V + 63) & ~63;
  const int t = threadIdx.x;
  const int g = t >> 6, lane = t & 63;
  const int hi = lane >> 5;            // which of the wave's 2 rows
  const int row = g * 2 + hi;          // local row 0..7
  const int c4 = lane & 31;            // float4 col within 128-col quarter
  const int q0 = qt * 8;

  __shared__ __align__(16) float w8[8][NK];

  // stage scores rows [q0..q0+7][0..Vc)
  for (int r = 0; r < 8; ++r) {
    const float4* src = (const float4*)&scores[(size_t)(b * NQ + q0 + r) * NK];
    for (int k4 = t; k4 < (Vc >> 2); k4 += 256)
      *(float4*)&w8[r][k4 * 4] = src[k4];
  }
  __syncthreads();

  // per-wave softmax on rows g*2, g*2+1 (in place, unnormalized e; rs kept)
  float rs0, rs1;
#pragma unroll 1
  for (int rr = 0; rr < 2; ++rr) {
    const int r = g * 2 + rr;
    float m = -1e30f;
    for (int k = lane; k < Vc; k += 64)
      m = fmaxf(m, (k < V) ? w8[r][k] : -1e30f);
    m = wave_rmax(m);
    float s = 0.f;
    for (int k = lane; k < Vc; k += 64) {
      float e = (k < V) ? __expf(w8[r][k] - m) : 0.f;
      w8[r][k] = e;
      s += e;
    }
    s = wave_rsum(s);
    float r_ = __builtin_amdgcn_rcpf(s);
    if (rr == 0) rs0 = r_; else rs1 = r_;
  }
  const float rs = hi ? rs1 : rs0;

  // PV: acc[row][vq*128 + c4*4 .. +3] over k   (w8 rows written by this wave)
  float4 acc = {0.f, 0.f, 0.f, 0.f};
  const float* vbase = values + (size_t)b * NK * NV + vq * 128 + c4 * 4;
#pragma unroll 8
  for (int kk = 0; kk < Vc; ++kk) {
    const float a = w8[row][kk];
    const float4 val = *(const float4*)&vbase[(size_t)kk * NV];
    acc.x += a * val.x; acc.y += a * val.y;
    acc.z += a * val.z; acc.w += a * val.w;
  }
  acc.x *= rs; acc.y *= rs; acc.z *= rs; acc.w *= rs;
  *(float4*)&out[(size_t)(b * NQ + q0 + row) * NV + vq * 128 + c4 * 4] = acc;
}

// =====================================================================
extern "C" void kernel_launch(void* const* d_in, const int* in_sizes, int n_in,
                              void* d_out, int out_size, void* d_ws, size_t ws_size,
                              hipStream_t stream) {
  const float* queries = (const float*)d_in[0];
  const float* keys    = (const float*)d_in[1];
  const float* values  = (const float*)d_in[2];
  const int*   vlens   = (const int*)d_in[3];
  const float* Wq      = (const float*)d_in[4];
  const float* Wk      = (const float*)d_in[5];
  const float* wv      = (const float*)d_in[6];
  float* out = (float*)d_out;

  float* ws     = (float*)d_ws;
  float* Eq     = ws;                          // NB*NQ*NH = 262144 f32
  float* EkT    = ws + 262144;                 // NB*NH*NK = 2097152 f32
  float* scores = ws + 262144 + 2097152;       // NB*NQ*NK = 1048576 f32

  proj_kernel<<<dim3(144, 4), dim3(256), 0, stream>>>(
      queries, keys, Wq, Wk, vlens, Eq, EkT);
  score_kernel<<<dim3(32, 4, 8), dim3(256), 0, stream>>>(
      Eq, EkT, wv, vlens, scores);
  softmax_pv_kernel<<<dim3(16, 4, 8), dim3(256), 0, stream>>>(
      scores, values, vlens, out);
}